// Round 5
// baseline (221.611 us; speedup 1.0000x reference)
//
#include <hip/hip_runtime.h>

#define B_  8
#define TQ  128
#define TV  128
#define DIM 512
#define UU  1024
#define NSPLIT 16            // u-splits for scores phase (u-chunk = 64)
#define NP  (B_ * TQ * TV)   // elements per partial plane
#define C2  2.885390081777927f   // 2*log2(e)
#define NBLK 512u
#define BSLOT 32             // uints per barrier slot (128 B line)
#define BSTRIDE (74 * BSLOT) // slots per barrier: 64 leaf + 8 mid + root + flag

typedef __attribute__((ext_vector_type(8))) short     short8;   // 8 bf16 (4 VGPRs)
typedef __attribute__((ext_vector_type(4))) float     f32x4;
typedef __attribute__((ext_vector_type(2))) float     f32x2;    // packed-f32 pair
typedef __attribute__((ext_vector_type(4))) unsigned short us4;

__device__ __forceinline__ unsigned short bf16_rtne(float x) {
    unsigned u = __float_as_uint(x);
    unsigned r = u + 0x7FFF + ((u >> 16) & 1);
    return (unsigned short)(r >> 16);
}

__device__ __forceinline__ f32x2 pkfma(f32x2 a, f32x2 b, f32x2 c) {
    return __builtin_elementwise_fma(a, b, c);
}

// Tree grid barrier (pre-zeroed by hipMemsetAsync).
// R4 post-mortem: 512 same-address agent RMWs serialize (~60ns each = 30us).
// 3-level fanout-8 tree: leaf(64 lines) -> mid(8) -> root -> flag.
// Per-level serialization = 8 RMWs; levels pipeline -> ~2-3us total.
// ACQ_REL adds chain happens-before leaf-last->mid-last->root-last->flag.
__device__ __forceinline__ void gridbar(unsigned* bar, int idx) {
    __syncthreads();
    if (threadIdx.x == 0) {
        unsigned* base = bar + idx * BSTRIDE;
        const int bid  = blockIdx.x;
        unsigned* leaf = base + (bid >> 3) * BSLOT;          // 64 lines
        unsigned* mid  = base + (64 + (bid >> 6)) * BSLOT;   // 8 lines
        unsigned* root = base + 72 * BSLOT;
        unsigned* flag = base + 73 * BSLOT;
        __threadfence();                         // release prior writes
        unsigned o = __hip_atomic_fetch_add(leaf, 1u, __ATOMIC_ACQ_REL,
                                            __HIP_MEMORY_SCOPE_AGENT);
        if (o == 7u) {
            o = __hip_atomic_fetch_add(mid, 1u, __ATOMIC_ACQ_REL,
                                       __HIP_MEMORY_SCOPE_AGENT);
            if (o == 7u) {
                o = __hip_atomic_fetch_add(root, 1u, __ATOMIC_ACQ_REL,
                                           __HIP_MEMORY_SCOPE_AGENT);
                if (o == 7u)
                    __hip_atomic_store(flag, 1u, __ATOMIC_RELEASE,
                                       __HIP_MEMORY_SCOPE_AGENT);
            }
        }
        while (__hip_atomic_load(flag, __ATOMIC_RELAXED,
                                 __HIP_MEMORY_SCOPE_AGENT) == 0u)
            __builtin_amdgcn_s_sleep(8);
        __threadfence();                         // acquire
    }
    __syncthreads();
}

// ---------------------------------------------------------------------------
// Mega-kernel: prep -> proj -> scores -> ctx with tree grid barriers.
// 512 blocks x 256 threads, 2 blocks/CU co-resident by construction.
// ---------------------------------------------------------------------------
#define PKP 72    // proj LDS pitch in shorts: 144 B
#define KSP 69    // scores ksT pitch in floats (odd -> 2-way write conflict max)
__global__ __launch_bounds__(256, 2) void k_mega(
    const float* __restrict__ Q, const float* __restrict__ Vv,
    const int*   __restrict__ mask,
    const float* __restrict__ W1, const float* __restrict__ W2,
    const float* __restrict__ scale,
    float* __restrict__ attn, float* __restrict__ ctx,
    float* __restrict__ Eq, float* __restrict__ Ek,
    float* __restrict__ part,
    unsigned short* __restrict__ Ab, unsigned short* __restrict__ Wh,
    unsigned* __restrict__ bar)
{
    __shared__ __align__(16) char smem[35328];   // union of all phase LDS

    const int tid = threadIdx.x;
    const int bid = blockIdx.x;

    // ================= phase 0: prep (cast + W transpose) =================
    // R4 post-mortem: old split (cast blocks tiny, transpose blocks 4 serial
    // tiles) skewed phase end; barrier turns skew into wall time. Now every
    // block does 2 cast chunks + 2 transpose tiles (uniform load).
    {
        #pragma unroll
        for (int it = 0; it < 2; ++it) {
            int idx = bid * 512 + it * 256 + tid;   // 512*512 = 2*131072 f4s
            int mat = idx >> 17;
            const float* src = mat ? Vv : Q;
            int off = (idx & 131071) * 4;
            float4 v = *(const float4*)&src[off];
            us4 h;
            h.x = bf16_rtne(v.x);
            h.y = bf16_rtne(v.y);
            h.z = bf16_rtne(v.z);
            h.w = bf16_rtne(v.w);
            *(us4*)&Ab[mat * 524288 + off] = h;
        }

        float (*ts)[36] = (float(*)[36])smem;
        #pragma unroll 1
        for (int it = 0; it < 2; ++it) {
            int b2   = bid * 2 + it;               // 0..1023
            int mat  = b2 >> 9;
            int tile = b2 & 511;                   // 32 n-tiles x 16 k-tiles
            int n0 = (tile & 31) * 32;
            int k0 = (tile >> 5) * 32;
            const float* W = mat ? W2 : W1;

            if (it) __syncthreads();               // protect ts reuse
            int kk = tid >> 3, n4 = (tid & 7) * 4;
            float4 w = *(const float4*)&W[(k0 + kk) * UU + n0 + n4];
            ts[n4 + 0][kk] = w.x; ts[n4 + 1][kk] = w.y;
            ts[n4 + 2][kk] = w.z; ts[n4 + 3][kk] = w.w;
            __syncthreads();

            int nn = tid >> 3, k4 = (tid & 7) * 4;
            float4 v = *(const float4*)&ts[nn][k4];
            us4 h;
            h.x = bf16_rtne(v.x);
            h.y = bf16_rtne(v.y);
            h.z = bf16_rtne(v.z);
            h.w = bf16_rtne(v.w);
            unsigned off = mat * 524288 + (n0 + nn) * 512 + k0 + k4;
            *(us4*)&Wh[off] = h;
        }
    }
    gridbar(bar, 0);

    // ================= phase 1: dual bf16 GEMM + exp2 epilogue ============
    {
        short* sAb = (short*)smem;
        short* sBh = (short*)(smem + 9216);

        const int wave = tid >> 6;
        const int lane = tid & 63;

        // XCD-aware decode: flat = j*8 + x
        const int x    = bid & 7;
        const int j    = bid >> 3;
        const int pair = x * 4 + (j >> 4);   // 0..31
        const int nt   = pair & 15;
        const int mat  = pair >> 4;
        const int mt   = j & 15;
        const int m0   = mt * 64;
        const int n0   = nt * 64;

        const unsigned mb = mat * 524288u;
        const int wm = (wave & 1) * 32;
        const int wn = (wave >> 1) * 32;

        const int sm = tid >> 2, sg = tid & 3;
        const unsigned short* gA = Ab + mb + (m0 + sm) * 512;
        const unsigned short* gB = Wh + mb + (n0 + sm) * 512;
        const int so0 = sm * PKP + sg * 8;
        const int so1 = sm * PKP + 32 + sg * 8;

        const int fr = lane & 15, fq = lane >> 4;
        const int aOff0 = (wm + fr) * PKP + fq * 8;
        const int aOff1 = (wm + 16 + fr) * PKP + fq * 8;
        const int bOff0 = (wn + fr) * PKP + fq * 8;
        const int bOff1 = (wn + 16 + fr) * PKP + fq * 8;

        f32x4 acc00 = {0.f, 0.f, 0.f, 0.f};
        f32x4 acc01 = {0.f, 0.f, 0.f, 0.f};
        f32x4 acc10 = {0.f, 0.f, 0.f, 0.f};
        f32x4 acc11 = {0.f, 0.f, 0.f, 0.f};

        int4 rA0, rA1, rB0, rB1;
        #define LOADALL(K)                                                   \
            rA0 = *(const int4*)(gA + (K) + sg * 8);                         \
            rA1 = *(const int4*)(gA + (K) + 32 + sg * 8);                    \
            rB0 = *(const int4*)(gB + (K) + sg * 8);                         \
            rB1 = *(const int4*)(gB + (K) + 32 + sg * 8);

        LOADALL(0)

        #pragma unroll 1
        for (int kc = 0; kc < 8; ++kc) {
            *(int4*)&sAb[so0] = rA0;  *(int4*)&sAb[so1] = rA1;
            *(int4*)&sBh[so0] = rB0;  *(int4*)&sBh[so1] = rB1;
            __syncthreads();

            if (kc < 7) { LOADALL((kc + 1) * 64) }

            #pragma unroll
            for (int ks = 0; ks < 2; ++ks) {
                const int o = ks * 32;
                short8 a0 = *(const short8*)&sAb[aOff0 + o];
                short8 a1 = *(const short8*)&sAb[aOff1 + o];
                short8 b0 = *(const short8*)&sBh[bOff0 + o];
                short8 b1 = *(const short8*)&sBh[bOff1 + o];

                acc00 = __builtin_amdgcn_mfma_f32_16x16x32_bf16(a0, b0, acc00, 0, 0, 0);
                acc01 = __builtin_amdgcn_mfma_f32_16x16x32_bf16(a0, b1, acc01, 0, 0, 0);
                acc10 = __builtin_amdgcn_mfma_f32_16x16x32_bf16(a1, b0, acc10, 0, 0, 0);
                acc11 = __builtin_amdgcn_mfma_f32_16x16x32_bf16(a1, b1, acc11, 0, 0, 0);
            }
            __syncthreads();
        }
        #undef LOADALL

        float* C = mat ? Ek : Eq;
        #pragma unroll
        for (int r = 0; r < 4; ++r) {
            int row0 = m0 + wm + fq * 4 + r;
            int row1 = row0 + 16;
            int col0 = n0 + wn + fr;
            C[row0 * UU + col0]      = __builtin_amdgcn_exp2f(C2 * acc00[r]);
            C[row0 * UU + col0 + 16] = __builtin_amdgcn_exp2f(C2 * acc01[r]);
            C[row1 * UU + col0]      = __builtin_amdgcn_exp2f(C2 * acc10[r]);
            C[row1 * UU + col0 + 16] = __builtin_amdgcn_exp2f(C2 * acc11[r]);
        }
    }
    gridbar(bar, 1);

    // ================= phase 2: partial scores (packed-f32) ===============
    {
        float (*qs)[68]   = (float(*)[68])smem;
        float (*ksT)[KSP] = (float(*)[KSP])(smem + 17408);   // [u][s], pitch 69
        float* ss         = (float*)(smem + 17408 + 64 * KSP * 4);

        const int tx  = tid & 15;            // s-group: s = s0 + tx*4 + jj
        const int ty  = tid >> 4;            // 0..15: q rows t0 + ty*4 + i
        const int bz  = bid >> 2;
        const int b   = bz & 7;
        const int us  = bz >> 3;             // 0..15
        const int t0  = ((bid >> 1) & 1) * 64;
        const int s0  = (bid & 1) * 64;
        const int u0  = us * (UU / NSPLIT);  // 64-wide u range

        {
            const int r  = tid >> 2;         // 0..63
            const int c0 = (tid & 3) * 16;   // 0,16,32,48
            const float* srq = &Eq[(b * TQ + t0 + r) * UU + u0 + c0];
            const float* srk = &Ek[(b * TV + s0 + r) * UU + u0 + c0];
            #pragma unroll
            for (int i = 0; i < 4; ++i) {
                *(float4*)&qs[r][c0 + i * 4] = *(const float4*)(srq + i * 4);
                float4 kv = *(const float4*)(srk + i * 4);
                ksT[c0 + i * 4 + 0][r] = kv.x;   // transpose into [u][s]
                ksT[c0 + i * 4 + 1][r] = kv.y;
                ksT[c0 + i * 4 + 2][r] = kv.z;
                ksT[c0 + i * 4 + 3][r] = kv.w;
            }
            if (tid < 16)
                *(float4*)&ss[tid * 4] = *(const float4*)&scale[u0 + tid * 4];
        }
        __syncthreads();

        f32x2 acc[4][2] = {};   // [i][s-pair]
        const f32x2 one2 = {1.f, 1.f};

        #pragma unroll 2
        for (int u4 = 0; u4 < 16; ++u4) {
            f32x2 kA[4][2];
            #pragma unroll
            for (int uu = 0; uu < 4; ++uu) {
                float4 kv = *(const float4*)&ksT[u4 * 4 + uu][tx * 4];
                kA[uu][0] = (f32x2){kv.x, kv.y};
                kA[uu][1] = (f32x2){kv.z, kv.w};
            }
            const float4 sv = *(const float4*)&ss[u4 * 4];
            const f32x2 sL0 = {sv.x, sv.x}, sH0 = {sv.y, sv.y};
            const f32x2 sL1 = {sv.z, sv.z}, sH1 = {sv.w, sv.w};

            #pragma unroll
            for (int i = 0; i < 4; ++i) {
                const float4 qv = *(const float4*)&qs[ty * 4 + i][u4 * 4];
                const f32x2 qL0 = {qv.x, qv.x}, qH0 = {qv.y, qv.y};
                const f32x2 qL1 = {qv.z, qv.z}, qH1 = {qv.w, qv.w};

                #pragma unroll
                for (int jp = 0; jp < 2; ++jp) {
                    f32x2 b1 = pkfma(qL0, kA[0][jp], one2);
                    f32x2 b2 = pkfma(qH0, kA[1][jp], one2);
                    f32x2 p  = b1 * b2;
                    f32x2 n  = pkfma(sH0, b1, sL0 * b2);
                    f32x2 r  = {__builtin_amdgcn_rcpf(p.x),
                                __builtin_amdgcn_rcpf(p.y)};
                    acc[i][jp] = pkfma(n, r, acc[i][jp]);
                    f32x2 b3 = pkfma(qL1, kA[2][jp], one2);
                    f32x2 b4 = pkfma(qH1, kA[3][jp], one2);
                    f32x2 p2 = b3 * b4;
                    f32x2 n2 = pkfma(sH1, b3, sL1 * b4);
                    f32x2 r2 = {__builtin_amdgcn_rcpf(p2.x),
                                __builtin_amdgcn_rcpf(p2.y)};
                    acc[i][jp] = pkfma(n2, r2, acc[i][jp]);
                }
            }
        }

        #pragma unroll
        for (int i = 0; i < 4; ++i) {
            float4 o = {acc[i][0].x, acc[i][0].y, acc[i][1].x, acc[i][1].y};
            *(float4*)&part[us * NP + (b * TQ + t0 + ty * 4 + i) * TV + s0 + tx * 4] = o;
        }
    }
    gridbar(bar, 2);

    // ================= phase 3: softmax + context =========================
    {
        float (*at)[12] = (float(*)[12])smem;   // [s][t 0..7 + pad]

        const int dc = bid & 3;            // d chunk of 128
        const int tt = (bid >> 2) & 15;    // t tile of 8
        const int b  = bid >> 6;
        const int t0 = tt * 8;
        const int rg = tid >> 5;           // 0..7
        const int ln = tid & 31;
        const int base = (b * TQ + t0 + rg) * TV;

        float4 p4 = {0.f, 0.f, 0.f, 0.f};
        #pragma unroll
        for (int i = 0; i < NSPLIT; ++i) {
            float4 v = *(const float4*)&part[i * NP + base + ln * 4];
            p4.x += v.x; p4.y += v.y; p4.z += v.z; p4.w += v.w;
        }
        const int4 mk = *(const int4*)&mask[b * TV + ln * 4];
        float x[4];
        x[0] = mk.x ? -2.f * p4.x : -1e9f;
        x[1] = mk.y ? -2.f * p4.y : -1e9f;
        x[2] = mk.z ? -2.f * p4.z : -1e9f;
        x[3] = mk.w ? -2.f * p4.w : -1e9f;

        float m = fmaxf(fmaxf(x[0], x[1]), fmaxf(x[2], x[3]));
        #pragma unroll
        for (int o = 16; o > 0; o >>= 1) m = fmaxf(m, __shfl_xor(m, o, 32));
        const float L2E = 1.4426950408889634f;
        float e[4], sum = 0.f;
        #pragma unroll
        for (int jj = 0; jj < 4; ++jj) {
            e[jj] = __builtin_amdgcn_exp2f((x[jj] - m) * L2E);
            sum += e[jj];
        }
        #pragma unroll
        for (int o = 16; o > 0; o >>= 1) sum += __shfl_xor(sum, o, 32);
        const float r = __builtin_amdgcn_rcpf(sum);

        float4 av = {e[0] * r, e[1] * r, e[2] * r, e[3] * r};
        at[ln * 4 + 0][rg] = av.x;
        at[ln * 4 + 1][rg] = av.y;
        at[ln * 4 + 2][rg] = av.z;
        at[ln * 4 + 3][rg] = av.w;
        if (dc == 0) *(float4*)&attn[base + ln * 4] = av;
        __syncthreads();

        const int d  = (tid & 127) + dc * 128;
        const int tg = tid >> 7;        // 0..1 -> rows tg*4..tg*4+3
        float acc[4] = {};
        const float* vp = &Vv[b * TV * DIM + d];
        #pragma unroll 4
        for (int s = 0; s < TV; ++s) {
            float v  = vp[s * DIM];
            float4 a = *(const float4*)&at[s][tg * 4];
            acc[0] = fmaf(a.x, v, acc[0]);
            acc[1] = fmaf(a.y, v, acc[1]);
            acc[2] = fmaf(a.z, v, acc[2]);
            acc[3] = fmaf(a.w, v, acc[3]);
        }
        #pragma unroll
        for (int jj = 0; jj < 4; ++jj) {
            int t = t0 + tg * 4 + jj;
            ctx[(b * TQ + t) * DIM + d] = acc[jj];
        }
    }
}
#undef PKP
#undef KSP

// ---------------------------------------------------------------------------
extern "C" void kernel_launch(void* const* d_in, const int* in_sizes, int n_in,
                              void* d_out, int out_size, void* d_ws, size_t ws_size,
                              hipStream_t stream)
{
    const float* query = (const float*)d_in[0];
    const float* value = (const float*)d_in[1];
    const int*   mask  = (const int*)d_in[2];
    const float* W1    = (const float*)d_in[3];
    const float* W2    = (const float*)d_in[4];
    const float* scale = (const float*)d_in[5];

    float* out  = (float*)d_out;
    float* ctx  = out;                    // [B, Tq, D]
    float* attn = out + B_ * TQ * DIM;    // [B, Tq, Tv]

    float* Eq   = (float*)d_ws;                                  // 4 MB
    float* Ek   = Eq + 1024 * 1024;                              // 4 MB
    float* part = Ek + 1024 * 1024;                              // 8 MB
    unsigned short* Ab = (unsigned short*)(part + NSPLIT * NP);  // 2 MB
    unsigned short* Wh = Ab + 2 * 1024 * 512;                    // 2 MB
    unsigned* bar = (unsigned*)(Wh + 2 * 1024 * 512);            // 3*BSTRIDE u32

    hipMemsetAsync(bar, 0, 3 * BSTRIDE * sizeof(unsigned), stream);
    hipLaunchKernelGGL(k_mega, dim3(512), dim3(256), 0, stream,
                       query, value, mask, W1, W2, scale, attn, ctx,
                       Eq, Ek, part, Ab, Wh, bar);
}

// Round 6
// 140.580 us; speedup vs baseline: 1.5764x; 1.5764x over previous
//
#include <hip/hip_runtime.h>

#define B_  8
#define TQ  128
#define TV  128
#define DIM 512
#define UU  1024
#define C2  2.885390081777927f   // 2*log2(e)

typedef __attribute__((ext_vector_type(8))) short     short8;   // 8 bf16 (4 VGPRs)
typedef __attribute__((ext_vector_type(4))) float     f32x4;
typedef __attribute__((ext_vector_type(2))) float     f32x2;    // packed-f32 pair
typedef __attribute__((ext_vector_type(4))) unsigned short us4;

__device__ __forceinline__ unsigned short bf16_rtne(float x) {
    unsigned u = __float_as_uint(x);
    unsigned r = u + 0x7FFF + ((u >> 16) & 1);
    return (unsigned short)(r >> 16);
}

__device__ __forceinline__ us4 cvt4(float4 v) {
    us4 h;
    h.x = bf16_rtne(v.x);
    h.y = bf16_rtne(v.y);
    h.z = bf16_rtne(v.z);
    h.w = bf16_rtne(v.w);
    return h;
}

__device__ __forceinline__ f32x2 pkfma(f32x2 a, f32x2 b, f32x2 c) {
    return __builtin_elementwise_fma(a, b, c);
}

// ---------------------------------------------------------------------------
// Kernel 1: dual bf16 GEMM + exp2 epilogue, with prep FUSED into staging.
//   Reads f32 Q/V and W1/W2 directly; casts to bf16 (RTNE, identical values
//   to the old k_prep) while staging into LDS.  W transpose [k][n]->[n][k]
//   done via scattered ds_write_b16 (64 lanes x 2B stride = 2 lanes/bank,
//   conflict-free).  MFMA loop and epilogue unchanged -> Eq/Ek bitwise
//   identical to the 4-kernel pipeline.
// ---------------------------------------------------------------------------
#define PKP 72   // shorts pitch: 144 B
__global__ __launch_bounds__(256, 2) void k_proj(
    const float* __restrict__ Q, const float* __restrict__ Vv,
    const float* __restrict__ W1, const float* __restrict__ W2,
    float* __restrict__ Eq, float* __restrict__ Ek)
{
    __shared__ short sAb[64 * PKP], sBh[64 * PKP];

    const int tid  = threadIdx.x;
    const int wave = tid >> 6;
    const int lane = tid & 63;

    // XCD-aware decode: flat = j*8 + x;  pair (nt,mat) = 4x + (j>>4); mt = j&15
    const int flat = blockIdx.x;
    const int x    = flat & 7;
    const int j    = flat >> 3;
    const int pair = x * 4 + (j >> 4);   // 0..31
    const int nt   = pair & 15;
    const int mat  = pair >> 4;
    const int mt   = j & 15;
    const int m0   = mt * 64;
    const int n0   = nt * 64;

    const float* Asrc = mat ? Vv : Q;    // [row][k]  (row-major, k=512)
    const float* Wsrc = mat ? W2 : W1;   // [k][n]    (k=512, n=1024)

    const int wm = (wave & 1) * 32;
    const int wn = (wave >> 1) * 32;

    // A staging: thread (sm = row 0..63, sg = col-group 0..3)
    const int sm = tid >> 2, sg = tid & 3;
    const float* gA = Asrc + (m0 + sm) * 512;
    const int so0 = sm * PKP + sg * 8;
    const int so1 = sm * PKP + 32 + sg * 8;

    // B staging: thread (kk = k-lane 0..63, ng = n-group 0..3 of 16)
    const int kk = tid & 63, ng = tid >> 6;
    const float* gW = Wsrc + n0 + ng * 16;

    const int fr = lane & 15, fq = lane >> 4;
    const int aOff0 = (wm + fr) * PKP + fq * 8;
    const int aOff1 = (wm + 16 + fr) * PKP + fq * 8;
    const int bOff0 = (wn + fr) * PKP + fq * 8;
    const int bOff1 = (wn + 16 + fr) * PKP + fq * 8;

    f32x4 acc00 = {0.f, 0.f, 0.f, 0.f};
    f32x4 acc01 = {0.f, 0.f, 0.f, 0.f};
    f32x4 acc10 = {0.f, 0.f, 0.f, 0.f};
    f32x4 acc11 = {0.f, 0.f, 0.f, 0.f};

    float4 a0, a1, a2, a3, w0, w1, w2, w3;
    #define LOADALL(K)                                                       \
        a0 = *(const float4*)(gA + (K) + sg * 8);                            \
        a1 = *(const float4*)(gA + (K) + sg * 8 + 4);                        \
        a2 = *(const float4*)(gA + (K) + 32 + sg * 8);                       \
        a3 = *(const float4*)(gA + (K) + 32 + sg * 8 + 4);                   \
        {                                                                    \
            const float* wr = gW + ((K) + kk) * UU;                          \
            w0 = *(const float4*)(wr);                                       \
            w1 = *(const float4*)(wr + 4);                                   \
            w2 = *(const float4*)(wr + 8);                                   \
            w3 = *(const float4*)(wr + 12);                                  \
        }

    LOADALL(0)

    #pragma unroll 1
    for (int kc = 0; kc < 8; ++kc) {
        // A: convert + contiguous 8B writes (same layout as before)
        *(us4*)&sAb[so0]     = cvt4(a0);
        *(us4*)&sAb[so0 + 4] = cvt4(a1);
        *(us4*)&sAb[so1]     = cvt4(a2);
        *(us4*)&sAb[so1 + 4] = cvt4(a3);
        // B: convert + transposed scatter [n][k]
        {
            us4 h[4] = {cvt4(w0), cvt4(w1), cvt4(w2), cvt4(w3)};
            #pragma unroll
            for (int g = 0; g < 4; ++g) {
                sBh[(ng * 16 + g * 4 + 0) * PKP + kk] = (short)h[g].x;
                sBh[(ng * 16 + g * 4 + 1) * PKP + kk] = (short)h[g].y;
                sBh[(ng * 16 + g * 4 + 2) * PKP + kk] = (short)h[g].z;
                sBh[(ng * 16 + g * 4 + 3) * PKP + kk] = (short)h[g].w;
            }
        }
        __syncthreads();

        if (kc < 7) { LOADALL((kc + 1) * 64) }

        #pragma unroll
        for (int ks = 0; ks < 2; ++ks) {
            const int o = ks * 32;
            short8 fa0 = *(const short8*)&sAb[aOff0 + o];
            short8 fa1 = *(const short8*)&sAb[aOff1 + o];
            short8 fb0 = *(const short8*)&sBh[bOff0 + o];
            short8 fb1 = *(const short8*)&sBh[bOff1 + o];

            acc00 = __builtin_amdgcn_mfma_f32_16x16x32_bf16(fa0, fb0, acc00, 0, 0, 0);
            acc01 = __builtin_amdgcn_mfma_f32_16x16x32_bf16(fa0, fb1, acc01, 0, 0, 0);
            acc10 = __builtin_amdgcn_mfma_f32_16x16x32_bf16(fa1, fb0, acc10, 0, 0, 0);
            acc11 = __builtin_amdgcn_mfma_f32_16x16x32_bf16(fa1, fb1, acc11, 0, 0, 0);
        }
        __syncthreads();
    }
    #undef LOADALL

    float* C = mat ? Ek : Eq;
    #pragma unroll
    for (int r = 0; r < 4; ++r) {
        int row0 = m0 + wm + fq * 4 + r;
        int row1 = row0 + 16;
        int col0 = n0 + wn + fr;
        C[row0 * UU + col0]      = __builtin_amdgcn_exp2f(C2 * acc00[r]);
        C[row0 * UU + col0 + 16] = __builtin_amdgcn_exp2f(C2 * acc01[r]);
        C[row1 * UU + col0]      = __builtin_amdgcn_exp2f(C2 * acc10[r]);
        C[row1 * UU + col0 + 16] = __builtin_amdgcn_exp2f(C2 * acc11[r]);
    }
}
#undef PKP

// ---------------------------------------------------------------------------
// Kernel 2: fused scores -> softmax -> attn,ctx.  No u-split across blocks,
// no `part` buffer, no grid sync.
// Block = (b = bid&7 [XCD-affine], 4 q-rows).  Grid 256, 256 threads.
// Thread = 1 t (wave id) x 1 s-pair (lane).  Full u=1024 loop in 16 LDS
// chunks; inner math = R2's packed pair-rcp sequence (identical op tree and
// u-order -> scores bitwise identical).  Softmax per row = one wave.
// ---------------------------------------------------------------------------
#define EKP 132   // pair-interleaved row pitch (f32): lane stride ≡ 4 banks
__global__ __launch_bounds__(256, 2) void k_sac(
    const float* __restrict__ Eq, const float* __restrict__ Ek,
    const float* __restrict__ scale, const int* __restrict__ mask,
    const float* __restrict__ Vv,
    float* __restrict__ attn, float* __restrict__ ctx)
{
    __shared__ float ek2[64][EKP];   // [s-pair][2u interleaved]  33.8 KB
    __shared__ float qs[4][68];
    __shared__ float ss[64];
    __shared__ float at[4][132];

    const int tid = threadIdx.x;
    const int bid = blockIdx.x;
    const int b   = bid & 7;         // XCD-affine: Ek[b] stays in one L2
    const int t0  = (bid >> 3) * 4;  // 4 q-rows per block
    const int sp  = tid & 63;        // s-pair: s = 2sp, 2sp+1
    const int tq  = tid >> 6;        // wave id = local q-row

    const int uu = tid >> 6;         // staging role: u-subchunk 0..3
    const float* ekrow0 = &Ek[(b * TV + 2 * sp) * UU + uu * 16];
    const float* ekrow1 = ekrow0 + UU;

    f32x2 acc = {0.f, 0.f};
    const f32x2 one2 = {1.f, 1.f};

    #pragma unroll 1
    for (int uc = 0; uc < 16; ++uc) {
        const int u0 = uc * 64;
        if (uc) __syncthreads();
        // ---- stage: k pair-interleaved, q rows, scale chunk ----
        #pragma unroll
        for (int c = 0; c < 4; ++c) {
            float4 ra = *(const float4*)(ekrow0 + u0 + c * 4);
            float4 rb = *(const float4*)(ekrow1 + u0 + c * 4);
            float4 lo = {ra.x, rb.x, ra.y, rb.y};
            float4 hi = {ra.z, rb.z, ra.w, rb.w};
            *(float4*)&ek2[sp][(uu * 16 + c * 4) * 2]     = lo;
            *(float4*)&ek2[sp][(uu * 16 + c * 4) * 2 + 4] = hi;
        }
        if (tid < 64) {
            const int r = tid >> 4, cs = (tid & 15) * 4;
            *(float4*)&qs[r][cs] =
                *(const float4*)&Eq[(b * TQ + t0 + r) * UU + u0 + cs];
        }
        if (tid < 16)
            *(float4*)&ss[tid * 4] = *(const float4*)&scale[u0 + tid * 4];
        __syncthreads();

        // ---- compute 16 u-quads ----
        #pragma unroll 4
        for (int u4 = 0; u4 < 16; ++u4) {
            float4 ka = *(const float4*)&ek2[sp][u4 * 8];
            float4 kb = *(const float4*)&ek2[sp][u4 * 8 + 4];
            f32x2 kA0 = {ka.x, ka.y}, kA1 = {ka.z, ka.w};
            f32x2 kA2 = {kb.x, kb.y}, kA3 = {kb.z, kb.w};
            float4 qv = *(const float4*)&qs[tq][u4 * 4];
            float4 sv = *(const float4*)&ss[u4 * 4];

            f32x2 b1 = pkfma((f32x2){qv.x, qv.x}, kA0, one2);
            f32x2 b2 = pkfma((f32x2){qv.y, qv.y}, kA1, one2);
            f32x2 p  = b1 * b2;
            f32x2 n  = pkfma((f32x2){sv.y, sv.y}, b1,
                             (f32x2){sv.x, sv.x} * b2);
            f32x2 r  = {__builtin_amdgcn_rcpf(p.x),
                        __builtin_amdgcn_rcpf(p.y)};
            acc = pkfma(n, r, acc);

            f32x2 b3 = pkfma((f32x2){qv.z, qv.z}, kA2, one2);
            f32x2 b4 = pkfma((f32x2){qv.w, qv.w}, kA3, one2);
            f32x2 p2 = b3 * b4;
            f32x2 n2 = pkfma((f32x2){sv.w, sv.w}, b3,
                             (f32x2){sv.z, sv.z} * b4);
            f32x2 r2 = {__builtin_amdgcn_rcpf(p2.x),
                        __builtin_amdgcn_rcpf(p2.y)};
            acc = pkfma(n2, r2, acc);
        }
    }

    // ---- softmax: row t0+tq owned entirely by wave tq ----
    const int2 mk = *(const int2*)&mask[b * TV + 2 * sp];
    float x0 = mk.x ? -2.f * acc.x : -1e9f;
    float x1 = mk.y ? -2.f * acc.y : -1e9f;
    float m = fmaxf(x0, x1);
    #pragma unroll
    for (int o = 32; o > 0; o >>= 1) m = fmaxf(m, __shfl_xor(m, o, 64));
    const float L2E = 1.4426950408889634f;
    float e0 = __builtin_amdgcn_exp2f((x0 - m) * L2E);
    float e1 = __builtin_amdgcn_exp2f((x1 - m) * L2E);
    float sum = e0 + e1;
    #pragma unroll
    for (int o = 32; o > 0; o >>= 1) sum += __shfl_xor(sum, o, 64);
    const float rs = __builtin_amdgcn_rcpf(sum);
    const float av0 = e0 * rs, av1 = e1 * rs;

    const int trow = t0 + tq;
    *(float2*)&attn[(b * TQ + trow) * TV + 2 * sp] = (float2){av0, av1};
    at[tq][2 * sp]     = av0;
    at[tq][2 * sp + 1] = av1;
    __syncthreads();

    // ---- PV: thread (tr = wave, 8 d); V reads fully coalesced ----
    const int tr = tid >> 6;
    const int dl = (tid & 63) * 8;
    float c0 = 0.f, c1 = 0.f, c2 = 0.f, c3 = 0.f;
    float c4 = 0.f, c5 = 0.f, c6 = 0.f, c7 = 0.f;
    const float* vp = &Vv[b * TV * DIM + dl];
    #pragma unroll 4
    for (int s = 0; s < TV; ++s) {
        float a  = at[tr][s];                       // LDS broadcast
        float4 v0 = *(const float4*)(vp + s * DIM);
        float4 v1 = *(const float4*)(vp + s * DIM + 4);
        c0 = fmaf(a, v0.x, c0); c1 = fmaf(a, v0.y, c1);
        c2 = fmaf(a, v0.z, c2); c3 = fmaf(a, v0.w, c3);
        c4 = fmaf(a, v1.x, c4); c5 = fmaf(a, v1.y, c5);
        c6 = fmaf(a, v1.z, c6); c7 = fmaf(a, v1.w, c7);
    }
    float* cp = &ctx[(b * TQ + t0 + tr) * DIM + dl];
    *(float4*)(cp)     = (float4){c0, c1, c2, c3};
    *(float4*)(cp + 4) = (float4){c4, c5, c6, c7};
}
#undef EKP

// ---------------------------------------------------------------------------
extern "C" void kernel_launch(void* const* d_in, const int* in_sizes, int n_in,
                              void* d_out, int out_size, void* d_ws, size_t ws_size,
                              hipStream_t stream)
{
    const float* query = (const float*)d_in[0];
    const float* value = (const float*)d_in[1];
    const int*   mask  = (const int*)d_in[2];
    const float* W1    = (const float*)d_in[3];
    const float* W2    = (const float*)d_in[4];
    const float* scale = (const float*)d_in[5];

    float* out  = (float*)d_out;
    float* ctx  = out;                    // [B, Tq, D]
    float* attn = out + B_ * TQ * DIM;    // [B, Tq, Tv]

    float* Eq = (float*)d_ws;             // 4 MB
    float* Ek = Eq + 1024 * 1024;         // 4 MB

    hipLaunchKernelGGL(k_proj, dim3(512), dim3(256), 0, stream,
                       query, value, W1, W2, Eq, Ek);
    hipLaunchKernelGGL(k_sac,  dim3(256), dim3(256), 0, stream,
                       Eq, Ek, scale, mask, value, attn, ctx);
}

// Round 7
// 140.439 us; speedup vs baseline: 1.5780x; 1.0010x over previous
//
#include <hip/hip_runtime.h>

#define B_  8
#define TQ  128
#define TV  128
#define DIM 512
#define UU  1024
#define C2  2.885390081777927f   // 2*log2(e)

typedef __attribute__((ext_vector_type(8))) short     short8;   // 8 bf16 (4 VGPRs)
typedef __attribute__((ext_vector_type(4))) float     f32x4;
typedef __attribute__((ext_vector_type(2))) float     f32x2;    // packed-f32 pair
typedef __attribute__((ext_vector_type(4))) unsigned short us4;

__device__ __forceinline__ unsigned short bf16_rtne(float x) {
    unsigned u = __float_as_uint(x);
    unsigned r = u + 0x7FFF + ((u >> 16) & 1);
    return (unsigned short)(r >> 16);
}

__device__ __forceinline__ us4 cvt4(float4 v) {
    us4 h;
    h.x = bf16_rtne(v.x);
    h.y = bf16_rtne(v.y);
    h.z = bf16_rtne(v.z);
    h.w = bf16_rtne(v.w);
    return h;
}

__device__ __forceinline__ f32x2 pkfma(f32x2 a, f32x2 b, f32x2 c) {
    return __builtin_elementwise_fma(a, b, c);
}

// ---------------------------------------------------------------------------
// Kernel 1: dual bf16 GEMM + exp2 epilogue, prep fused into staging.
// UNCHANGED from R6 (passed, ~20us).
// ---------------------------------------------------------------------------
#define PKP 72   // shorts pitch: 144 B
__global__ __launch_bounds__(256, 2) void k_proj(
    const float* __restrict__ Q, const float* __restrict__ Vv,
    const float* __restrict__ W1, const float* __restrict__ W2,
    float* __restrict__ Eq, float* __restrict__ Ek)
{
    __shared__ short sAb[64 * PKP], sBh[64 * PKP];

    const int tid  = threadIdx.x;
    const int wave = tid >> 6;
    const int lane = tid & 63;

    const int flat = blockIdx.x;
    const int x    = flat & 7;
    const int j    = flat >> 3;
    const int pair = x * 4 + (j >> 4);   // 0..31
    const int nt   = pair & 15;
    const int mat  = pair >> 4;
    const int mt   = j & 15;
    const int m0   = mt * 64;
    const int n0   = nt * 64;

    const float* Asrc = mat ? Vv : Q;    // [row][k]
    const float* Wsrc = mat ? W2 : W1;   // [k][n]

    const int wm = (wave & 1) * 32;
    const int wn = (wave >> 1) * 32;

    const int sm = tid >> 2, sg = tid & 3;
    const float* gA = Asrc + (m0 + sm) * 512;
    const int so0 = sm * PKP + sg * 8;
    const int so1 = sm * PKP + 32 + sg * 8;

    const int kk = tid & 63, ng = tid >> 6;
    const float* gW = Wsrc + n0 + ng * 16;

    const int fr = lane & 15, fq = lane >> 4;
    const int aOff0 = (wm + fr) * PKP + fq * 8;
    const int aOff1 = (wm + 16 + fr) * PKP + fq * 8;
    const int bOff0 = (wn + fr) * PKP + fq * 8;
    const int bOff1 = (wn + 16 + fr) * PKP + fq * 8;

    f32x4 acc00 = {0.f, 0.f, 0.f, 0.f};
    f32x4 acc01 = {0.f, 0.f, 0.f, 0.f};
    f32x4 acc10 = {0.f, 0.f, 0.f, 0.f};
    f32x4 acc11 = {0.f, 0.f, 0.f, 0.f};

    float4 a0, a1, a2, a3, w0, w1, w2, w3;
    #define LOADALL(K)                                                       \
        a0 = *(const float4*)(gA + (K) + sg * 8);                            \
        a1 = *(const float4*)(gA + (K) + sg * 8 + 4);                        \
        a2 = *(const float4*)(gA + (K) + 32 + sg * 8);                       \
        a3 = *(const float4*)(gA + (K) + 32 + sg * 8 + 4);                   \
        {                                                                    \
            const float* wr = gW + ((K) + kk) * UU;                          \
            w0 = *(const float4*)(wr);                                       \
            w1 = *(const float4*)(wr + 4);                                   \
            w2 = *(const float4*)(wr + 8);                                   \
            w3 = *(const float4*)(wr + 12);                                  \
        }

    LOADALL(0)

    #pragma unroll 1
    for (int kc = 0; kc < 8; ++kc) {
        *(us4*)&sAb[so0]     = cvt4(a0);
        *(us4*)&sAb[so0 + 4] = cvt4(a1);
        *(us4*)&sAb[so1]     = cvt4(a2);
        *(us4*)&sAb[so1 + 4] = cvt4(a3);
        {
            us4 h[4] = {cvt4(w0), cvt4(w1), cvt4(w2), cvt4(w3)};
            #pragma unroll
            for (int g = 0; g < 4; ++g) {
                sBh[(ng * 16 + g * 4 + 0) * PKP + kk] = (short)h[g].x;
                sBh[(ng * 16 + g * 4 + 1) * PKP + kk] = (short)h[g].y;
                sBh[(ng * 16 + g * 4 + 2) * PKP + kk] = (short)h[g].z;
                sBh[(ng * 16 + g * 4 + 3) * PKP + kk] = (short)h[g].w;
            }
        }
        __syncthreads();

        if (kc < 7) { LOADALL((kc + 1) * 64) }

        #pragma unroll
        for (int ks = 0; ks < 2; ++ks) {
            const int o = ks * 32;
            short8 fa0 = *(const short8*)&sAb[aOff0 + o];
            short8 fa1 = *(const short8*)&sAb[aOff1 + o];
            short8 fb0 = *(const short8*)&sBh[bOff0 + o];
            short8 fb1 = *(const short8*)&sBh[bOff1 + o];

            acc00 = __builtin_amdgcn_mfma_f32_16x16x32_bf16(fa0, fb0, acc00, 0, 0, 0);
            acc01 = __builtin_amdgcn_mfma_f32_16x16x32_bf16(fa0, fb1, acc01, 0, 0, 0);
            acc10 = __builtin_amdgcn_mfma_f32_16x16x32_bf16(fa1, fb0, acc10, 0, 0, 0);
            acc11 = __builtin_amdgcn_mfma_f32_16x16x32_bf16(fa1, fb1, acc11, 0, 0, 0);
        }
        __syncthreads();
    }
    #undef LOADALL

    float* C = mat ? Ek : Eq;
    #pragma unroll
    for (int r = 0; r < 4; ++r) {
        int row0 = m0 + wm + fq * 4 + r;
        int row1 = row0 + 16;
        int col0 = n0 + wn + fr;
        C[row0 * UU + col0]      = __builtin_amdgcn_exp2f(C2 * acc00[r]);
        C[row0 * UU + col0 + 16] = __builtin_amdgcn_exp2f(C2 * acc01[r]);
        C[row1 * UU + col0]      = __builtin_amdgcn_exp2f(C2 * acc10[r]);
        C[row1 * UU + col0 + 16] = __builtin_amdgcn_exp2f(C2 * acc11[r]);
    }
}
#undef PKP

// ---------------------------------------------------------------------------
// Kernel 2 v2: fused scores -> softmax -> attn,ctx.
// R6 post-mortem: grid 256 = 1 wave/SIMD, VALUBusy 18% -> latency-bound.
// v2: grid 512 (2 q-rows/block -> 2 blocks/CU, 2 waves/SIMD); thread =
// (row, u-half, s-pair) so per-thread acc chain drops 512 -> 2x64 links;
// halves combined via LDS. Staging/LDS layout/math identical to R6.
// ---------------------------------------------------------------------------
#define EKP 132   // pair-interleaved row pitch (f32)
__global__ __launch_bounds__(256, 2) void k_sac(
    const float* __restrict__ Eq, const float* __restrict__ Ek,
    const float* __restrict__ scale, const int* __restrict__ mask,
    const float* __restrict__ Vv,
    float* __restrict__ attn, float* __restrict__ ctx)
{
    __shared__ float ek2[64][EKP];   // 33.8 KB
    __shared__ float qs[2][68];
    __shared__ float ss[64];
    __shared__ float at[2][132];
    __shared__ f32x2 pacc[2][2][64]; // [row][u-half][s-pair]

    const int tid = threadIdx.x;
    const int bid = blockIdx.x;
    const int b   = bid & 7;         // XCD-affine: Ek[b] in one L2
    const int t0  = (bid >> 3) * 2;  // 2 q-rows per block
    const int sp  = tid & 63;        // s-pair: s = 2sp, 2sp+1
    const int r   = tid >> 7;        // q-row (uniform per wave)
    const int uh  = (tid >> 6) & 1;  // u-half of chunk (uniform per wave)

    const int uu = tid >> 6;         // staging role: u-subchunk 0..3
    const float* ekrow0 = &Ek[(b * TV + 2 * sp) * UU + uu * 16];
    const float* ekrow1 = ekrow0 + UU;

    f32x2 acc0 = {0.f, 0.f}, acc1 = {0.f, 0.f};
    const f32x2 one2 = {1.f, 1.f};

    #pragma unroll 1
    for (int uc = 0; uc < 16; ++uc) {
        const int u0 = uc * 64;
        if (uc) __syncthreads();
        // ---- stage: k pair-interleaved, q rows, scale chunk ----
        #pragma unroll
        for (int c = 0; c < 4; ++c) {
            float4 ra = *(const float4*)(ekrow0 + u0 + c * 4);
            float4 rb = *(const float4*)(ekrow1 + u0 + c * 4);
            float4 lo = {ra.x, rb.x, ra.y, rb.y};
            float4 hi = {ra.z, rb.z, ra.w, rb.w};
            *(float4*)&ek2[sp][(uu * 16 + c * 4) * 2]     = lo;
            *(float4*)&ek2[sp][(uu * 16 + c * 4) * 2 + 4] = hi;
        }
        if (tid < 32) {
            const int rr = tid >> 4, cs = (tid & 15) * 4;
            *(float4*)&qs[rr][cs] =
                *(const float4*)&Eq[(b * TQ + t0 + rr) * UU + u0 + cs];
        }
        if (tid < 16)
            *(float4*)&ss[tid * 4] = *(const float4*)&scale[u0 + tid * 4];
        __syncthreads();

        // ---- compute own 8 u-quads (u-half uh of the 64-u chunk) ----
        #pragma unroll
        for (int u4 = 0; u4 < 8; ++u4) {
            const int g = uh * 8 + u4;
            float4 ka = *(const float4*)&ek2[sp][g * 8];
            float4 kb = *(const float4*)&ek2[sp][g * 8 + 4];
            f32x2 kA0 = {ka.x, ka.y}, kA1 = {ka.z, ka.w};
            f32x2 kA2 = {kb.x, kb.y}, kA3 = {kb.z, kb.w};
            float4 qv = *(const float4*)&qs[r][g * 4];   // broadcast
            float4 sv = *(const float4*)&ss[g * 4];      // broadcast

            f32x2 b1 = pkfma((f32x2){qv.x, qv.x}, kA0, one2);
            f32x2 b2 = pkfma((f32x2){qv.y, qv.y}, kA1, one2);
            f32x2 p  = b1 * b2;
            f32x2 n  = pkfma((f32x2){sv.y, sv.y}, b1,
                             (f32x2){sv.x, sv.x} * b2);
            f32x2 rc = {__builtin_amdgcn_rcpf(p.x),
                        __builtin_amdgcn_rcpf(p.y)};
            acc0 = pkfma(n, rc, acc0);

            f32x2 b3 = pkfma((f32x2){qv.z, qv.z}, kA2, one2);
            f32x2 b4 = pkfma((f32x2){qv.w, qv.w}, kA3, one2);
            f32x2 p2 = b3 * b4;
            f32x2 n2 = pkfma((f32x2){sv.w, sv.w}, b3,
                             (f32x2){sv.z, sv.z} * b4);
            f32x2 rc2 = {__builtin_amdgcn_rcpf(p2.x),
                         __builtin_amdgcn_rcpf(p2.y)};
            acc1 = pkfma(n2, rc2, acc1);
        }
    }

    pacc[r][uh][sp] = acc0 + acc1;
    __syncthreads();

    // ---- softmax: waves 0,1 -> rows 0,1 ----
    if (tid < 128) {
        const int rr  = tid >> 6;
        const int sp2 = tid & 63;
        f32x2 pa = pacc[rr][0][sp2];
        f32x2 pb = pacc[rr][1][sp2];
        f32x2 acc = {pa.x + pb.x, pa.y + pb.y};

        const int2 mk = *(const int2*)&mask[b * TV + 2 * sp2];
        float x0 = mk.x ? -2.f * acc.x : -1e9f;
        float x1 = mk.y ? -2.f * acc.y : -1e9f;
        float m = fmaxf(x0, x1);
        #pragma unroll
        for (int o = 32; o > 0; o >>= 1) m = fmaxf(m, __shfl_xor(m, o, 64));
        const float L2E = 1.4426950408889634f;
        float e0 = __builtin_amdgcn_exp2f((x0 - m) * L2E);
        float e1 = __builtin_amdgcn_exp2f((x1 - m) * L2E);
        float sum = e0 + e1;
        #pragma unroll
        for (int o = 32; o > 0; o >>= 1) sum += __shfl_xor(sum, o, 64);
        const float rs = __builtin_amdgcn_rcpf(sum);
        const float av0 = e0 * rs, av1 = e1 * rs;

        *(float2*)&attn[(b * TQ + t0 + rr) * TV + 2 * sp2] =
            (float2){av0, av1};
        at[rr][2 * sp2]     = av0;
        at[rr][2 * sp2 + 1] = av1;
    }
    __syncthreads();

    // ---- PV: thread (pr = tid>>7, 4 d); V reads fully coalesced ----
    const int pr = tid >> 7;
    const int dl = (tid & 127) * 4;
    float c0 = 0.f, c1 = 0.f, c2 = 0.f, c3 = 0.f;
    const float* vp = &Vv[b * TV * DIM + dl];
    #pragma unroll 4
    for (int s = 0; s < TV; ++s) {
        float a  = at[pr][s];                       // LDS broadcast
        float4 v = *(const float4*)(vp + s * DIM);
        c0 = fmaf(a, v.x, c0); c1 = fmaf(a, v.y, c1);
        c2 = fmaf(a, v.z, c2); c3 = fmaf(a, v.w, c3);
    }
    *(float4*)&ctx[(b * TQ + t0 + pr) * DIM + dl] = (float4){c0, c1, c2, c3};
}
#undef EKP

// ---------------------------------------------------------------------------
extern "C" void kernel_launch(void* const* d_in, const int* in_sizes, int n_in,
                              void* d_out, int out_size, void* d_ws, size_t ws_size,
                              hipStream_t stream)
{
    const float* query = (const float*)d_in[0];
    const float* value = (const float*)d_in[1];
    const int*   mask  = (const int*)d_in[2];
    const float* W1    = (const float*)d_in[3];
    const float* W2    = (const float*)d_in[4];
    const float* scale = (const float*)d_in[5];

    float* out  = (float*)d_out;
    float* ctx  = out;                    // [B, Tq, D]
    float* attn = out + B_ * TQ * DIM;    // [B, Tq, Tv]

    float* Eq = (float*)d_ws;             // 4 MB
    float* Ek = Eq + 1024 * 1024;         // 4 MB

    hipLaunchKernelGGL(k_proj, dim3(512), dim3(256), 0, stream,
                       query, value, W1, W2, Eq, Ek);
    hipLaunchKernelGGL(k_sac,  dim3(512), dim3(256), 0, stream,
                       Eq, Ek, scale, mask, value, attn, ctx);
}